// Round 7
// baseline (288.674 us; speedup 1.0000x reference)
//
#include <hip/hip_runtime.h>
#include <hip/hip_bf16.h>

#define N_NODESC 50000
#define N_EDGESC 1600000
#define NGC 1024
#define NPC 8
#define NBIN 196          // dst>>8 buckets (256 nodes each)
#define NBLKE 391         // edge chunks of 4096

typedef __attribute__((ext_vector_type(8))) short bf16x8;
typedef __attribute__((ext_vector_type(4))) float f32x4;

__device__ inline ushort f2bf(float f) {
  union { float f; uint u; } v; v.f = f;
  uint u = v.u;
  u += 0x7FFF + ((u >> 16) & 1);
  return (ushort)(u >> 16);
}
__device__ inline float bflo(uint u) {
  union { uint u; float f; } v; v.u = u << 16; return v.f;
}
__device__ inline float bfhi(uint u) {
  union { uint u; float f; } v; v.u = u & 0xFFFF0000u; return v.f;
}

// ---------------- fused prep: weights + features + edge histogram ----------
__global__ __launch_bounds__(256) void megaprep(
    const float* __restrict__ qa1w, const float* __restrict__ qa2w,
    const float* __restrict__ lin1w, const float* __restrict__ lin2w,
    ushort* __restrict__ qe1, ushort* __restrict__ qe2,
    ushort* __restrict__ l1w, ushort* __restrict__ l2w,
    const int* __restrict__ x, const float* __restrict__ e24,
    const float* __restrict__ e72, ushort* __restrict__ feat,
    const int* __restrict__ dst, int* __restrict__ bh) {
  int bid = blockIdx.x, t = threadIdx.x;
  if (bid < 256) {
    const float* qw = (bid < 128) ? qa1w : qa2w;
    ushort* eff = (bid < 128) ? qe1 : qe2;
    int k = (bid & 127) * 2 + (t >> 7);
    int j = t & 127;
    const float* r = qw + (size_t)k * 256;
    float v;
    if (j < 64) v = r[j] + r[128 + j] + r[192 + j];
    else { int j2 = j - 64; v = r[64 + j2] + r[128 + j2] + 2.0f * r[192 + j2]; }
    eff[(size_t)k * 128 + j] = f2bf(v);
  } else if (bid < 304) {
    int i = (bid - 256) * 256 + t;  // < 12288 = 128*96
    int r = i / 96, c = i - r * 96;
    l1w[i] = (c < 68) ? f2bf(lin1w[(size_t)r * 68 + c]) : (ushort)0;
  } else if (bid < 432) {
    int r = bid - 304;
    l2w[(size_t)r * 256 + t] = f2bf(lin2w[(size_t)r * 256 + t]);
  } else if (bid < 1456) {
    const int stride = 1024 * 256;
    for (int i = (bid - 432) * 256 + t; i < N_NODESC * 96; i += stride) {
      int n = i / 96, tt = i - n * 96;
      float v = 0.f;
      if (tt < 4) v = (float)x[n * 4 + tt];
      else if (tt < 36) { int kk = tt - 4;  int f = kk >> 3, c = kk & 7; v = e24[(x[n * 4 + f] % 24) * 8 + c]; }
      else if (tt < 68) { int kk = tt - 36; int f = kk >> 3, c = kk & 7; v = e72[(x[n * 4 + f] % 72) * 8 + c]; }
      feat[i] = f2bf(v);
    }
  } else {
    __shared__ int hist[NBIN];
    int blk = bid - 1456;
    if (t < NBIN) hist[t] = 0;
    __syncthreads();
    int base = blk * 4096;
#pragma unroll
    for (int i = 0; i < 16; ++i) {
      int idx = base + i * 256 + t;
      if (idx < N_EDGESC) atomicAdd(&hist[dst[idx] >> 8], 1);
    }
    __syncthreads();
    if (t < NBIN) bh[(size_t)t * NBLKE + blk] = hist[t];
  }
}

// ---------------- CSR: per-bin scan ----------------
__global__ __launch_bounds__(64) void csr_scan_bins(int* __restrict__ bh, int* __restrict__ bt) {
  int bin = blockIdx.x;
  int lane = threadIdx.x;
  int carry = 0;
  int* row = bh + (size_t)bin * NBLKE;
  for (int c = 0; c < NBLKE; c += 64) {
    int j = c + lane;
    int v = (j < NBLKE) ? row[j] : 0;
    int incl = v;
#pragma unroll
    for (int off = 1; off < 64; off <<= 1) {
      int u = __shfl_up(incl, off, 64);
      if (lane >= off) incl += u;
    }
    if (j < NBLKE) row[j] = carry + incl - v;
    carry += __shfl(incl, 63, 64);
  }
  if (lane == 0) bt[bin] = carry;
}

// ---------------- shared GEMM body (W staged in swizzled LDS) ---------------
// C[M,NC] = act(A @ W^T + b). ASPLIT/CSPLIT: [2][N_NODESC][64] ushort layout.
template <int K, int ASPLIT, int CSPLIT>
__device__ __forceinline__ void gemm_body(ushort* ws, int bx, int by,
    const ushort* __restrict__ A, const ushort* __restrict__ W,
    const float* __restrict__ bias, ushort* __restrict__ C,
    int M, int NC, int relu) {
  int tid = threadIdx.x;
  int lane = tid & 63;
  int wv = tid >> 6;
  int rbase = bx * 128 + wv * 32;
  int colt = by * 128;
  int r16 = lane & 15;
  int kg = (lane >> 4) * 8;

  const char* wt = (const char*)(W + (size_t)colt * K);
#pragma unroll
  for (int i = 0; i < K / 16; ++i) {
    int o = (i * 256 + tid) * 16;
    int col = o / (2 * K);
    int sw = o ^ ((col & 7) << 4);
    *(bf16x8*)((char*)ws + sw) = *(const bf16x8*)(wt + o);
  }
  __syncthreads();

  f32x4 acc[2][8];
#pragma unroll
  for (int m = 0; m < 2; ++m)
#pragma unroll
    for (int n = 0; n < 8; ++n) acc[m][n] = (f32x4){0.f, 0.f, 0.f, 0.f};

  for (int k0 = 0; k0 < K; k0 += 32) {
    int ks = k0 + kg;
    bf16x8 a[2], b[8];
#pragma unroll
    for (int m = 0; m < 2; ++m) {
      int rr = rbase + m * 16 + r16;
      if (rr >= M) rr = M - 1;
      const ushort* ap = ASPLIT ? (A + ((size_t)(ks >> 6) * N_NODESC + rr) * 64 + (ks & 63))
                                : (A + (size_t)rr * K + ks);
      a[m] = *(const bf16x8*)ap;
    }
#pragma unroll
    for (int n = 0; n < 8; ++n) {
      int cl = n * 16 + r16;
      int byte = (cl * 2 * K + ks * 2) ^ ((cl & 7) << 4);
      b[n] = *(const bf16x8*)((const char*)ws + byte);
    }
#pragma unroll
    for (int m = 0; m < 2; ++m)
#pragma unroll
      for (int n = 0; n < 8; ++n)
        acc[m][n] = __builtin_amdgcn_mfma_f32_16x16x32_bf16(a[m], b[n], acc[m][n], 0, 0, 0);
  }

  int rowoff = (lane >> 4) * 4;
#pragma unroll
  for (int m = 0; m < 2; ++m) {
#pragma unroll
    for (int j = 0; j < 4; ++j) {
      int row = rbase + m * 16 + rowoff + j;
      if (row >= M) continue;
#pragma unroll
      for (int n = 0; n < 8; ++n) {
        int col = colt + n * 16 + r16;
        float v = acc[m][n][j] + bias[col];
        if (relu) v = fmaxf(v, 0.f);
        size_t idx = CSPLIT ? ((size_t)(col >> 6) * N_NODESC + row) * 64 + (col & 63)
                            : (size_t)row * NC + col;
        C[idx] = f2bf(v);
      }
    }
  }
}

template <int K, int ASPLIT, int CSPLIT>
__global__ __launch_bounds__(256, 2) void mfma_gemm_lds(
    const ushort* __restrict__ A, const ushort* __restrict__ W,
    const float* __restrict__ bias, ushort* __restrict__ C,
    int M, int NC, int relu) {
  __shared__ ushort ws[128 * K];
  gemm_body<K, ASPLIT, CSPLIT>(ws, blockIdx.x, blockIdx.y, A, W, bias, C, M, NC, relu);
}

// ---------------- fused: csr_scatter (blocks < NBLKE) ∥ lin1 GEMM ----------
__global__ __launch_bounds__(256, 2) void scatter_lin1(
    const int* __restrict__ src, const int* __restrict__ dst,
    const int* __restrict__ bh, const int* __restrict__ bt, uint* __restrict__ tmp,
    const ushort* __restrict__ feat, const ushort* __restrict__ l1w,
    const float* __restrict__ lin1b, ushort* __restrict__ linx) {
  __shared__ ushort ws[128 * 96];
  int bid = blockIdx.x, t = threadIdx.x;
  if (bid < NBLKE) {
    int* sc = (int*)ws;
    int* cur = sc + 256;
    int v = (t < NBIN) ? bt[t] : 0;
    sc[t] = v;
    __syncthreads();
    for (int off = 1; off < 256; off <<= 1) {
      int u = (t >= off) ? sc[t - off] : 0;
      __syncthreads();
      sc[t] += u;
      __syncthreads();
    }
    if (t < NBIN) cur[t] = (sc[t] - v) + bh[(size_t)t * NBLKE + bid];
    __syncthreads();
    int base = bid * 4096;
#pragma unroll
    for (int i = 0; i < 16; ++i) {
      int idx = base + i * 256 + t;
      if (idx < N_EDGESC) {
        int d = dst[idx];
        uint p = ((uint)d << 16) | (uint)src[idx];
        int pos = atomicAdd(&cur[d >> 8], 1);
        tmp[pos] = p;
      }
    }
  } else {
    gemm_body<96, 0, 1>(ws, bid - NBLKE, 0, feat, l1w, lin1b, linx, N_NODESC, 128, 0);
  }
}

// ---------------- per-bucket counting sort -> elist (ushort) + rp -----------
__global__ __launch_bounds__(256) void csr_bucket_sort(const uint* __restrict__ tmp,
                                                       const int* __restrict__ bt,
                                                       ushort* __restrict__ elist,
                                                       int* __restrict__ rp) {
  __shared__ int sc[256];
  __shared__ int cnt[256];
  int b = blockIdx.x, t = threadIdx.x;
  int v = (t < NBIN) ? bt[t] : 0;
  sc[t] = v;
  __syncthreads();
  for (int off = 1; off < 256; off <<= 1) {
    int u = (t >= off) ? sc[t - off] : 0;
    __syncthreads();
    sc[t] += u;
    __syncthreads();
  }
  int base = (b == 0) ? 0 : sc[b - 1];
  int end = sc[b];
  int total = sc[NBIN - 1];
  __syncthreads();
  cnt[t] = 0;
  __syncthreads();
  for (int i = base + t; i < end; i += 256)
    atomicAdd(&cnt[(tmp[i] >> 16) & 255], 1);
  __syncthreads();
  int cv = cnt[t];
  sc[t] = cv;
  __syncthreads();
  for (int off = 1; off < 256; off <<= 1) {
    int u = (t >= off) ? sc[t - off] : 0;
    __syncthreads();
    sc[t] += u;
    __syncthreads();
  }
  int excl = sc[t] - cv;
  int node = (b << 8) + t;
  if (node < N_NODESC) rp[node] = base + excl;
  if (b == NBIN - 1 && t == 0) rp[N_NODESC] = total;
  cnt[t] = base + excl;  // global cursor
  __syncthreads();
  for (int i = base + t; i < end; i += 256) {
    uint p = tmp[i];
    int pos = atomicAdd(&cnt[(p >> 16) & 255], 1);
    elist[pos] = (ushort)(p & 0xFFFFu);
  }
}

// ---------------- aggregation, col-halves [2][N][32]u, 2 temporal passes ----
// Wave per node; 32-lane half handles one edge per load (one full 128B line).
__global__ __launch_bounds__(256) void aggregate_h(const uint* __restrict__ lx,
                                                   const int* __restrict__ rp,
                                                   const ushort* __restrict__ elist,
                                                   uint* __restrict__ h2) {
  const int BPP = N_NODESC / 4;  // 12500 blocks per pass
  int bid = blockIdx.x;
  int pass = bid / BPP;
  int nb = bid - pass * BPP;
  const uint* T = lx + (size_t)pass * N_NODESC * 32;
  uint* O = h2 + (size_t)pass * N_NODESC * 32;
  int wv = threadIdx.x >> 6, lane = threadIdx.x & 63;
  int half = lane >> 5, c = lane & 31;
  int n = nb * 4 + wv;
  int beg = rp[n], end = rp[n + 1];
  float a0 = 0.f, a1 = 0.f;
  int e = beg + half;
  for (; e + 14 < end; e += 16) {
    int s0 = elist[e], s1 = elist[e + 2], s2 = elist[e + 4], s3 = elist[e + 6];
    int s4 = elist[e + 8], s5 = elist[e + 10], s6 = elist[e + 12], s7 = elist[e + 14];
    uint u0 = T[(size_t)s0 * 32 + c];
    uint u1 = T[(size_t)s1 * 32 + c];
    uint u2 = T[(size_t)s2 * 32 + c];
    uint u3 = T[(size_t)s3 * 32 + c];
    uint u4 = T[(size_t)s4 * 32 + c];
    uint u5 = T[(size_t)s5 * 32 + c];
    uint u6 = T[(size_t)s6 * 32 + c];
    uint u7 = T[(size_t)s7 * 32 + c];
    a0 += bflo(u0) + bflo(u1) + bflo(u2) + bflo(u3);
    a1 += bfhi(u0) + bfhi(u1) + bfhi(u2) + bfhi(u3);
    a0 += bflo(u4) + bflo(u5) + bflo(u6) + bflo(u7);
    a1 += bfhi(u4) + bfhi(u5) + bfhi(u6) + bfhi(u7);
  }
  for (; e < end; e += 2) {
    uint u = T[(size_t)elist[e] * 32 + c];
    a0 += bflo(u);
    a1 += bfhi(u);
  }
  a0 += __shfl_xor(a0, 32);
  a1 += __shfl_xor(a1, 32);
  if (half == 0) {
    uint su = T[(size_t)n * 32 + c];
    O[(size_t)n * 32 + c] = (uint)f2bf(a0 + 2.f * bflo(su)) |
                            ((uint)f2bf(a1 + 2.f * bfhi(su)) << 16);
  }
}

// ---------------- global mean pool (batch sorted), bf16 input ---------------
__global__ __launch_bounds__(256) void pool2(const uint* __restrict__ h,
                                             const int* __restrict__ batch,
                                             float* __restrict__ g) {
  int gg = blockIdx.x;
  int t = threadIdx.x;
  int j = t & 127, rg = t >> 7;
  int lo = 0, hi = N_NODESC;
  while (lo < hi) { int mid = (lo + hi) >> 1; if (batch[mid] < gg) lo = mid + 1; else hi = mid; }
  int beg = lo;
  hi = N_NODESC;
  while (lo < hi) { int mid = (lo + hi) >> 1; if (batch[mid] < gg + 1) lo = mid + 1; else hi = mid; }
  int end = lo;
  float a0 = 0.f, a1 = 0.f;
  int n = beg + rg;
  for (; n + 2 < end; n += 4) {
    uint u = h[(size_t)n * 128 + j];
    uint u2 = h[(size_t)(n + 2) * 128 + j];
    a0 += bflo(u) + bflo(u2);
    a1 += bfhi(u) + bfhi(u2);
  }
  if (n < end) {
    uint u = h[(size_t)n * 128 + j];
    a0 += bflo(u);
    a1 += bfhi(u);
  }
  __shared__ float s0[128], s1[128];
  if (rg == 1) { s0[j] = a0; s1[j] = a1; }
  __syncthreads();
  if (rg == 0) {
    a0 += s0[j];
    a1 += s1[j];
    float cfac = fmaxf((float)(end - beg), 1.0f);
    g[(size_t)gg * 256 + 2 * j] = a0 / cfac;
    g[(size_t)gg * 256 + 2 * j + 1] = a1 / cfac;
  }
}

// ---------------- per-property heads (8 graphs per block) -------------------
__global__ __launch_bounds__(128) void head_kernel(const float* __restrict__ g,
    const float* __restrict__ w1, const float* __restrict__ b1,
    const float* __restrict__ w2, const float* __restrict__ b2,
    float* __restrict__ out) {
  int p = blockIdx.y;
  int g0 = blockIdx.x * 8;
  int t = threadIdx.x;
  __shared__ float gs[8][256];
  for (int i = t; i < 8 * 256; i += 128)
    gs[i >> 8][i & 255] = g[(size_t)(g0 + (i >> 8)) * 256 + (i & 255)];
  __syncthreads();
  const float4* w4 = (const float4*)(w1 + ((size_t)p * 128 + t) * 256);
  float bv = b1[p * 128 + t];
  float acc[8];
#pragma unroll
  for (int q = 0; q < 8; ++q) acc[q] = bv;
  for (int d4 = 0; d4 < 64; ++d4) {
    float4 wv = w4[d4];
#pragma unroll
    for (int q = 0; q < 8; ++q) {
      acc[q] += gs[q][d4 * 4 + 0] * wv.x + gs[q][d4 * 4 + 1] * wv.y +
                gs[q][d4 * 4 + 2] * wv.z + gs[q][d4 * 4 + 3] * wv.w;
    }
  }
  float w2v = w2[p * 128 + t];
  __shared__ float red[2][8];
  int wave = t >> 6, lane = t & 63;
#pragma unroll
  for (int q = 0; q < 8; ++q) {
    float v = fmaxf(acc[q], 0.f) * w2v;
    for (int o = 32; o > 0; o >>= 1) v += __shfl_down(v, o, 64);
    if (lane == 0) red[wave][q] = v;
  }
  __syncthreads();
  if (t < 8) out[(size_t)(g0 + t) * 8 + p] = red[0][t] + red[1][t] + b2[p];
}

extern "C" void kernel_launch(void* const* d_in, const int* in_sizes, int n_in,
                              void* d_out, int out_size, void* d_ws, size_t ws_size,
                              hipStream_t stream) {
  const int*   x     = (const int*)d_in[0];
  const int*   ei    = (const int*)d_in[1];
  const int*   batch = (const int*)d_in[2];
  const float* emb24 = (const float*)d_in[3];
  const float* emb72 = (const float*)d_in[4];
  const float* lin1w = (const float*)d_in[5];
  const float* lin1b = (const float*)d_in[6];
  const float* qa1w  = (const float*)d_in[7];
  const float* qa1b  = (const float*)d_in[8];
  const float* lin2w = (const float*)d_in[9];
  const float* lin2b = (const float*)d_in[10];
  const float* qa2w  = (const float*)d_in[11];
  const float* qa2b  = (const float*)d_in[12];
  const float* hw1   = (const float*)d_in[13];
  const float* hb1   = (const float*)d_in[14];
  const float* hw2   = (const float*)d_in[15];
  const float* hb2   = (const float*)d_in[16];
  float* out = (float*)d_out;

  const int* srcv = ei;
  const int* dstv = ei + N_EDGESC;

  char* wsb = (char*)d_ws;
  size_t off = 0;
  auto alloc = [&](size_t b) { char* p = wsb + off; off += (b + 255) & ~(size_t)255; return p; };
  ushort* feat  = (ushort*)alloc((size_t)N_NODESC * 96 * 2);
  ushort* linx  = (ushort*)alloc((size_t)N_NODESC * 128 * 2);   // SPLIT [2][N][64]
  ushort* h2    = (ushort*)alloc((size_t)N_NODESC * 128 * 2);   // SPLIT [2][N][64]
  ushort* h     = (ushort*)alloc((size_t)N_NODESC * 256 * 2);   // row-major
  float*  gbuf  = (float*)alloc((size_t)NGC * 256 * 4);
  ushort* qe1   = (ushort*)alloc(256 * 128 * 2);
  ushort* qe2   = (ushort*)alloc(256 * 128 * 2);
  ushort* l1w   = (ushort*)alloc(128 * 96 * 2);
  ushort* l2w   = (ushort*)alloc(128 * 256 * 2);
  int*    rp    = (int*)alloc((size_t)(N_NODESC + 1) * 4);
  ushort* elist = (ushort*)alloc((size_t)N_EDGESC * 2);
  int*    bh    = (int*)alloc((size_t)NBIN * NBLKE * 4);
  int*    bt    = (int*)alloc((size_t)NBIN * 4);
  uint*   tmp   = (uint*)h;  // alias: h not written until qa1 (after CSR done)

  // fused prep: weights + features + histogram
  megaprep<<<1847, 256, 0, stream>>>(qa1w, qa2w, lin1w, lin2w, qe1, qe2, l1w, l2w,
                                     x, emb24, emb72, feat, dstv, bh);
  csr_scan_bins<<<NBIN, 64, 0, stream>>>(bh, bt);

  int gm = (N_NODESC + 127) / 128;  // 391

  // scatter ∥ lin1 GEMM (independent)
  scatter_lin1<<<NBLKE + gm, 256, 0, stream>>>(srcv, dstv, bh, bt, tmp,
                                               feat, l1w, lin1b, linx);
  csr_bucket_sort<<<NBIN, 256, 0, stream>>>(tmp, bt, elist, rp);

  // layer 1
  aggregate_h<<<(N_NODESC / 4) * 2, 256, 0, stream>>>((const uint*)linx, rp, elist, (uint*)h2);
  mfma_gemm_lds<128, 1, 0><<<dim3(gm, 2), 256, 0, stream>>>(h2, qe1, qa1b, h, N_NODESC, 256, 1);

  // layer 2
  mfma_gemm_lds<256, 0, 1><<<dim3(gm, 1), 256, 0, stream>>>(h, l2w, lin2b, linx, N_NODESC, 128, 0);
  aggregate_h<<<(N_NODESC / 4) * 2, 256, 0, stream>>>((const uint*)linx, rp, elist, (uint*)h2);
  mfma_gemm_lds<128, 1, 0><<<dim3(gm, 2), 256, 0, stream>>>(h2, qe2, qa2b, h, N_NODESC, 256, 1);

  // pool + heads
  pool2<<<NGC, 256, 0, stream>>>((const uint*)h, batch, gbuf);
  head_kernel<<<dim3(NGC / 8, NPC), 128, 0, stream>>>(gbuf, hw1, hb1, hw2, hb2, out);
}

// Round 8
// 266.518 us; speedup vs baseline: 1.0831x; 1.0831x over previous
//
#include <hip/hip_runtime.h>
#include <hip/hip_bf16.h>

#define N_NODESC 50000
#define N_EDGESC 1600000
#define NGC 1024
#define NPC 8
#define NBIN 196          // dst>>8 buckets (256 nodes each)
#define NBLKE 391         // edge chunks of 4096

typedef __attribute__((ext_vector_type(8))) short bf16x8;
typedef __attribute__((ext_vector_type(4))) float f32x4;

__device__ inline ushort f2bf(float f) {
  union { float f; uint u; } v; v.f = f;
  uint u = v.u;
  u += 0x7FFF + ((u >> 16) & 1);
  return (ushort)(u >> 16);
}
__device__ inline float bflo(uint u) {
  union { uint u; float f; } v; v.u = u << 16; return v.f;
}
__device__ inline float bfhi(uint u) {
  union { uint u; float f; } v; v.u = u & 0xFFFF0000u; return v.f;
}

// ---------------- fused prep: weights + features + edge histogram ----------
__global__ __launch_bounds__(256) void megaprep(
    const float* __restrict__ qa1w, const float* __restrict__ qa2w,
    const float* __restrict__ lin1w, const float* __restrict__ lin2w,
    ushort* __restrict__ qe1, ushort* __restrict__ qe2,
    ushort* __restrict__ l1w, ushort* __restrict__ l2w,
    const int* __restrict__ x, const float* __restrict__ e24,
    const float* __restrict__ e72, ushort* __restrict__ feat,
    const int* __restrict__ dst, int* __restrict__ bh) {
  int bid = blockIdx.x, t = threadIdx.x;
  if (bid < 256) {
    const float* qw = (bid < 128) ? qa1w : qa2w;
    ushort* eff = (bid < 128) ? qe1 : qe2;
    int k = (bid & 127) * 2 + (t >> 7);
    int j = t & 127;
    const float* r = qw + (size_t)k * 256;
    float v;
    if (j < 64) v = r[j] + r[128 + j] + r[192 + j];
    else { int j2 = j - 64; v = r[64 + j2] + r[128 + j2] + 2.0f * r[192 + j2]; }
    eff[(size_t)k * 128 + j] = f2bf(v);
  } else if (bid < 304) {
    int i = (bid - 256) * 256 + t;  // < 12288 = 128*96
    int r = i / 96, c = i - r * 96;
    l1w[i] = (c < 68) ? f2bf(lin1w[(size_t)r * 68 + c]) : (ushort)0;
  } else if (bid < 432) {
    int r = bid - 304;
    l2w[(size_t)r * 256 + t] = f2bf(lin2w[(size_t)r * 256 + t]);
  } else if (bid < 1456) {
    const int stride = 1024 * 256;
    for (int i = (bid - 432) * 256 + t; i < N_NODESC * 96; i += stride) {
      int n = i / 96, tt = i - n * 96;
      float v = 0.f;
      if (tt < 4) v = (float)x[n * 4 + tt];
      else if (tt < 36) { int kk = tt - 4;  int f = kk >> 3, c = kk & 7; v = e24[(x[n * 4 + f] % 24) * 8 + c]; }
      else if (tt < 68) { int kk = tt - 36; int f = kk >> 3, c = kk & 7; v = e72[(x[n * 4 + f] % 72) * 8 + c]; }
      feat[i] = f2bf(v);
    }
  } else {
    __shared__ int hist[NBIN];
    int blk = bid - 1456;
    if (t < NBIN) hist[t] = 0;
    __syncthreads();
    int base = blk * 4096;
#pragma unroll
    for (int i = 0; i < 16; ++i) {
      int idx = base + i * 256 + t;
      if (idx < N_EDGESC) atomicAdd(&hist[dst[idx] >> 8], 1);
    }
    __syncthreads();
    if (t < NBIN) bh[(size_t)t * NBLKE + blk] = hist[t];
  }
}

// ---------------- CSR: per-bin scan ----------------
__global__ __launch_bounds__(64) void csr_scan_bins(int* __restrict__ bh, int* __restrict__ bt) {
  int bin = blockIdx.x;
  int lane = threadIdx.x;
  int carry = 0;
  int* row = bh + (size_t)bin * NBLKE;
  for (int c = 0; c < NBLKE; c += 64) {
    int j = c + lane;
    int v = (j < NBLKE) ? row[j] : 0;
    int incl = v;
#pragma unroll
    for (int off = 1; off < 64; off <<= 1) {
      int u = __shfl_up(incl, off, 64);
      if (lane >= off) incl += u;
    }
    if (j < NBLKE) row[j] = carry + incl - v;
    carry += __shfl(incl, 63, 64);
  }
  if (lane == 0) bt[bin] = carry;
}

// ---------------- shared GEMM body (W staged in swizzled LDS) ---------------
template <int K>
__device__ __forceinline__ void gemm_body(ushort* ws, int bx, int by,
    const ushort* __restrict__ A, const ushort* __restrict__ W,
    const float* __restrict__ bias, ushort* __restrict__ C,
    int M, int NC, int relu) {
  int tid = threadIdx.x;
  int lane = tid & 63;
  int wv = tid >> 6;
  int rbase = bx * 128 + wv * 32;
  int colt = by * 128;
  int r16 = lane & 15;
  int kg = (lane >> 4) * 8;

  const char* wt = (const char*)(W + (size_t)colt * K);
#pragma unroll
  for (int i = 0; i < K / 16; ++i) {
    int o = (i * 256 + tid) * 16;
    int col = o / (2 * K);
    int sw = o ^ ((col & 7) << 4);
    *(bf16x8*)((char*)ws + sw) = *(const bf16x8*)(wt + o);
  }
  __syncthreads();

  f32x4 acc[2][8];
#pragma unroll
  for (int m = 0; m < 2; ++m)
#pragma unroll
    for (int n = 0; n < 8; ++n) acc[m][n] = (f32x4){0.f, 0.f, 0.f, 0.f};

  for (int k0 = 0; k0 < K; k0 += 32) {
    int ks = k0 + kg;
    bf16x8 a[2], b[8];
#pragma unroll
    for (int m = 0; m < 2; ++m) {
      int rr = rbase + m * 16 + r16;
      if (rr >= M) rr = M - 1;
      a[m] = *(const bf16x8*)(A + (size_t)rr * K + ks);
    }
#pragma unroll
    for (int n = 0; n < 8; ++n) {
      int cl = n * 16 + r16;
      int byte = (cl * 2 * K + ks * 2) ^ ((cl & 7) << 4);
      b[n] = *(const bf16x8*)((const char*)ws + byte);
    }
#pragma unroll
    for (int m = 0; m < 2; ++m)
#pragma unroll
      for (int n = 0; n < 8; ++n)
        acc[m][n] = __builtin_amdgcn_mfma_f32_16x16x32_bf16(a[m], b[n], acc[m][n], 0, 0, 0);
  }

  int rowoff = (lane >> 4) * 4;
#pragma unroll
  for (int m = 0; m < 2; ++m) {
#pragma unroll
    for (int j = 0; j < 4; ++j) {
      int row = rbase + m * 16 + rowoff + j;
      if (row >= M) continue;
#pragma unroll
      for (int n = 0; n < 8; ++n) {
        int col = colt + n * 16 + r16;
        float v = acc[m][n][j] + bias[col];
        if (relu) v = fmaxf(v, 0.f);
        C[(size_t)row * NC + col] = f2bf(v);
      }
    }
  }
}

template <int K>
__global__ __launch_bounds__(256, 2) void mfma_gemm_lds(
    const ushort* __restrict__ A, const ushort* __restrict__ W,
    const float* __restrict__ bias, ushort* __restrict__ C,
    int M, int NC, int relu) {
  __shared__ ushort ws[128 * K];
  gemm_body<K>(ws, blockIdx.x, blockIdx.y, A, W, bias, C, M, NC, relu);
}

// ---------------- fused: csr_scatter (blocks < NBLKE) ∥ lin1 GEMM ----------
__global__ __launch_bounds__(256, 2) void scatter_lin1(
    const int* __restrict__ src, const int* __restrict__ dst,
    const int* __restrict__ bh, const int* __restrict__ bt, uint* __restrict__ tmp,
    const ushort* __restrict__ feat, const ushort* __restrict__ l1w,
    const float* __restrict__ lin1b, ushort* __restrict__ linx) {
  __shared__ ushort ws[128 * 96];
  int bid = blockIdx.x, t = threadIdx.x;
  if (bid < NBLKE) {
    int* sc = (int*)ws;
    int* cur = sc + 256;
    int v = (t < NBIN) ? bt[t] : 0;
    sc[t] = v;
    __syncthreads();
    for (int off = 1; off < 256; off <<= 1) {
      int u = (t >= off) ? sc[t - off] : 0;
      __syncthreads();
      sc[t] += u;
      __syncthreads();
    }
    if (t < NBIN) cur[t] = (sc[t] - v) + bh[(size_t)t * NBLKE + bid];
    __syncthreads();
    int base = bid * 4096;
#pragma unroll
    for (int i = 0; i < 16; ++i) {
      int idx = base + i * 256 + t;
      if (idx < N_EDGESC) {
        int d = dst[idx];
        uint p = ((uint)d << 16) | (uint)src[idx];
        int pos = atomicAdd(&cur[d >> 8], 1);
        tmp[pos] = p;
      }
    }
  } else {
    gemm_body<96>(ws, bid - NBLKE, 0, feat, l1w, lin1b, linx, N_NODESC, 128, 0);
  }
}

// ---------------- per-bucket counting sort -> elist (ushort) + rp -----------
__global__ __launch_bounds__(256) void csr_bucket_sort(const uint* __restrict__ tmp,
                                                       const int* __restrict__ bt,
                                                       ushort* __restrict__ elist,
                                                       int* __restrict__ rp) {
  __shared__ int sc[256];
  __shared__ int cnt[256];
  int b = blockIdx.x, t = threadIdx.x;
  int v = (t < NBIN) ? bt[t] : 0;
  sc[t] = v;
  __syncthreads();
  for (int off = 1; off < 256; off <<= 1) {
    int u = (t >= off) ? sc[t - off] : 0;
    __syncthreads();
    sc[t] += u;
    __syncthreads();
  }
  int base = (b == 0) ? 0 : sc[b - 1];
  int end = sc[b];
  int total = sc[NBIN - 1];
  __syncthreads();
  cnt[t] = 0;
  __syncthreads();
  for (int i = base + t; i < end; i += 256)
    atomicAdd(&cnt[(tmp[i] >> 16) & 255], 1);
  __syncthreads();
  int cv = cnt[t];
  sc[t] = cv;
  __syncthreads();
  for (int off = 1; off < 256; off <<= 1) {
    int u = (t >= off) ? sc[t - off] : 0;
    __syncthreads();
    sc[t] += u;
    __syncthreads();
  }
  int excl = sc[t] - cv;
  int node = (b << 8) + t;
  if (node < N_NODESC) rp[node] = base + excl;
  if (b == NBIN - 1 && t == 0) rp[N_NODESC] = total;
  cnt[t] = base + excl;  // global cursor
  __syncthreads();
  for (int i = base + t; i < end; i += 256) {
    uint p = tmp[i];
    int pos = atomicAdd(&cnt[(p >> 16) & 255], 1);
    elist[pos] = (ushort)(p & 0xFFFFu);
  }
}

// ---------------- aggregation: h2[n] = 2*linx[n] + sum_{e->n} linx[src] -----
// Row-major [N][128] bf16. uint2 loads: 32-lane half-wave covers one full
// 256B row; wave processes 2 edges per load instruction, 8 loads in flight.
__global__ __launch_bounds__(256) void aggregate_v(const uint2* __restrict__ lx,
                                                   const int* __restrict__ rp,
                                                   const ushort* __restrict__ elist,
                                                   uint2* __restrict__ h2) {
  int wv = threadIdx.x >> 6, lane = threadIdx.x & 63;
  int half = lane >> 5, c = lane & 31;  // c: uint2 index within row (0..31)
  int n = blockIdx.x * 4 + wv;
  int beg = rp[n], end = rp[n + 1];
  float a0 = 0.f, a1 = 0.f, a2 = 0.f, a3 = 0.f;
  int e = beg + half;
  for (; e + 14 < end; e += 16) {
    int s0 = __builtin_nontemporal_load(elist + e);
    int s1 = __builtin_nontemporal_load(elist + e + 2);
    int s2 = __builtin_nontemporal_load(elist + e + 4);
    int s3 = __builtin_nontemporal_load(elist + e + 6);
    int s4 = __builtin_nontemporal_load(elist + e + 8);
    int s5 = __builtin_nontemporal_load(elist + e + 10);
    int s6 = __builtin_nontemporal_load(elist + e + 12);
    int s7 = __builtin_nontemporal_load(elist + e + 14);
    uint2 u0 = lx[(size_t)s0 * 32 + c];
    uint2 u1 = lx[(size_t)s1 * 32 + c];
    uint2 u2 = lx[(size_t)s2 * 32 + c];
    uint2 u3 = lx[(size_t)s3 * 32 + c];
    uint2 u4 = lx[(size_t)s4 * 32 + c];
    uint2 u5 = lx[(size_t)s5 * 32 + c];
    uint2 u6 = lx[(size_t)s6 * 32 + c];
    uint2 u7 = lx[(size_t)s7 * 32 + c];
    a0 += bflo(u0.x) + bflo(u1.x) + bflo(u2.x) + bflo(u3.x);
    a1 += bfhi(u0.x) + bfhi(u1.x) + bfhi(u2.x) + bfhi(u3.x);
    a2 += bflo(u0.y) + bflo(u1.y) + bflo(u2.y) + bflo(u3.y);
    a3 += bfhi(u0.y) + bfhi(u1.y) + bfhi(u2.y) + bfhi(u3.y);
    a0 += bflo(u4.x) + bflo(u5.x) + bflo(u6.x) + bflo(u7.x);
    a1 += bfhi(u4.x) + bfhi(u5.x) + bfhi(u6.x) + bfhi(u7.x);
    a2 += bflo(u4.y) + bflo(u5.y) + bflo(u6.y) + bflo(u7.y);
    a3 += bfhi(u4.y) + bfhi(u5.y) + bfhi(u6.y) + bfhi(u7.y);
  }
  for (; e < end; e += 2) {
    int s = __builtin_nontemporal_load(elist + e);
    uint2 u = lx[(size_t)s * 32 + c];
    a0 += bflo(u.x);
    a1 += bfhi(u.x);
    a2 += bflo(u.y);
    a3 += bfhi(u.y);
  }
  a0 += __shfl_xor(a0, 32);
  a1 += __shfl_xor(a1, 32);
  a2 += __shfl_xor(a2, 32);
  a3 += __shfl_xor(a3, 32);
  if (half == 0) {
    uint2 su = lx[(size_t)n * 32 + c];
    uint2 w;
    w.x = (uint)f2bf(a0 + 2.f * bflo(su.x)) | ((uint)f2bf(a1 + 2.f * bfhi(su.x)) << 16);
    w.y = (uint)f2bf(a2 + 2.f * bflo(su.y)) | ((uint)f2bf(a3 + 2.f * bfhi(su.y)) << 16);
    h2[(size_t)n * 32 + c] = w;
  }
}

// ---------------- global mean pool (batch sorted), bf16 input ---------------
__global__ __launch_bounds__(256) void pool2(const uint* __restrict__ h,
                                             const int* __restrict__ batch,
                                             float* __restrict__ g) {
  int gg = blockIdx.x;
  int t = threadIdx.x;
  int j = t & 127, rg = t >> 7;
  int lo = 0, hi = N_NODESC;
  while (lo < hi) { int mid = (lo + hi) >> 1; if (batch[mid] < gg) lo = mid + 1; else hi = mid; }
  int beg = lo;
  hi = N_NODESC;
  while (lo < hi) { int mid = (lo + hi) >> 1; if (batch[mid] < gg + 1) lo = mid + 1; else hi = mid; }
  int end = lo;
  float a0 = 0.f, a1 = 0.f;
  int n = beg + rg;
  for (; n + 2 < end; n += 4) {
    uint u = h[(size_t)n * 128 + j];
    uint u2 = h[(size_t)(n + 2) * 128 + j];
    a0 += bflo(u) + bflo(u2);
    a1 += bfhi(u) + bfhi(u2);
  }
  if (n < end) {
    uint u = h[(size_t)n * 128 + j];
    a0 += bflo(u);
    a1 += bfhi(u);
  }
  __shared__ float s0[128], s1[128];
  if (rg == 1) { s0[j] = a0; s1[j] = a1; }
  __syncthreads();
  if (rg == 0) {
    a0 += s0[j];
    a1 += s1[j];
    float cfac = fmaxf((float)(end - beg), 1.0f);
    g[(size_t)gg * 256 + 2 * j] = a0 / cfac;
    g[(size_t)gg * 256 + 2 * j + 1] = a1 / cfac;
  }
}

// ---------------- per-property heads (8 graphs per block) -------------------
__global__ __launch_bounds__(128) void head_kernel(const float* __restrict__ g,
    const float* __restrict__ w1, const float* __restrict__ b1,
    const float* __restrict__ w2, const float* __restrict__ b2,
    float* __restrict__ out) {
  int p = blockIdx.y;
  int g0 = blockIdx.x * 8;
  int t = threadIdx.x;
  __shared__ float gs[8][256];
  for (int i = t; i < 8 * 256; i += 128)
    gs[i >> 8][i & 255] = g[(size_t)(g0 + (i >> 8)) * 256 + (i & 255)];
  __syncthreads();
  const float4* w4 = (const float4*)(w1 + ((size_t)p * 128 + t) * 256);
  float bv = b1[p * 128 + t];
  float acc[8];
#pragma unroll
  for (int q = 0; q < 8; ++q) acc[q] = bv;
  for (int d4 = 0; d4 < 64; ++d4) {
    float4 wv = w4[d4];
#pragma unroll
    for (int q = 0; q < 8; ++q) {
      acc[q] += gs[q][d4 * 4 + 0] * wv.x + gs[q][d4 * 4 + 1] * wv.y +
                gs[q][d4 * 4 + 2] * wv.z + gs[q][d4 * 4 + 3] * wv.w;
    }
  }
  float w2v = w2[p * 128 + t];
  __shared__ float red[2][8];
  int wave = t >> 6, lane = t & 63;
#pragma unroll
  for (int q = 0; q < 8; ++q) {
    float v = fmaxf(acc[q], 0.f) * w2v;
    for (int o = 32; o > 0; o >>= 1) v += __shfl_down(v, o, 64);
    if (lane == 0) red[wave][q] = v;
  }
  __syncthreads();
  if (t < 8) out[(size_t)(g0 + t) * 8 + p] = red[0][t] + red[1][t] + b2[p];
}

extern "C" void kernel_launch(void* const* d_in, const int* in_sizes, int n_in,
                              void* d_out, int out_size, void* d_ws, size_t ws_size,
                              hipStream_t stream) {
  const int*   x     = (const int*)d_in[0];
  const int*   ei    = (const int*)d_in[1];
  const int*   batch = (const int*)d_in[2];
  const float* emb24 = (const float*)d_in[3];
  const float* emb72 = (const float*)d_in[4];
  const float* lin1w = (const float*)d_in[5];
  const float* lin1b = (const float*)d_in[6];
  const float* qa1w  = (const float*)d_in[7];
  const float* qa1b  = (const float*)d_in[8];
  const float* lin2w = (const float*)d_in[9];
  const float* lin2b = (const float*)d_in[10];
  const float* qa2w  = (const float*)d_in[11];
  const float* qa2b  = (const float*)d_in[12];
  const float* hw1   = (const float*)d_in[13];
  const float* hb1   = (const float*)d_in[14];
  const float* hw2   = (const float*)d_in[15];
  const float* hb2   = (const float*)d_in[16];
  float* out = (float*)d_out;

  const int* srcv = ei;
  const int* dstv = ei + N_EDGESC;

  char* wsb = (char*)d_ws;
  size_t off = 0;
  auto alloc = [&](size_t b) { char* p = wsb + off; off += (b + 255) & ~(size_t)255; return p; };
  ushort* feat  = (ushort*)alloc((size_t)N_NODESC * 96 * 2);
  ushort* linx  = (ushort*)alloc((size_t)N_NODESC * 128 * 2);   // row-major [N][128]
  ushort* h2    = (ushort*)alloc((size_t)N_NODESC * 128 * 2);   // row-major
  ushort* h     = (ushort*)alloc((size_t)N_NODESC * 256 * 2);   // row-major
  float*  gbuf  = (float*)alloc((size_t)NGC * 256 * 4);
  ushort* qe1   = (ushort*)alloc(256 * 128 * 2);
  ushort* qe2   = (ushort*)alloc(256 * 128 * 2);
  ushort* l1w   = (ushort*)alloc(128 * 96 * 2);
  ushort* l2w   = (ushort*)alloc(128 * 256 * 2);
  int*    rp    = (int*)alloc((size_t)(N_NODESC + 1) * 4);
  ushort* elist = (ushort*)alloc((size_t)N_EDGESC * 2);
  int*    bh    = (int*)alloc((size_t)NBIN * NBLKE * 4);
  int*    bt    = (int*)alloc((size_t)NBIN * 4);
  uint*   tmp   = (uint*)h;  // alias: h not written until qa1 (after CSR done)

  // fused prep: weights + features + histogram
  megaprep<<<1847, 256, 0, stream>>>(qa1w, qa2w, lin1w, lin2w, qe1, qe2, l1w, l2w,
                                     x, emb24, emb72, feat, dstv, bh);
  csr_scan_bins<<<NBIN, 64, 0, stream>>>(bh, bt);

  int gm = (N_NODESC + 127) / 128;  // 391

  // scatter ∥ lin1 GEMM (independent)
  scatter_lin1<<<NBLKE + gm, 256, 0, stream>>>(srcv, dstv, bh, bt, tmp,
                                               feat, l1w, lin1b, linx);
  csr_bucket_sort<<<NBIN, 256, 0, stream>>>(tmp, bt, elist, rp);

  // layer 1
  aggregate_v<<<N_NODESC / 4, 256, 0, stream>>>((const uint2*)linx, rp, elist, (uint2*)h2);
  mfma_gemm_lds<128><<<dim3(gm, 2), 256, 0, stream>>>(h2, qe1, qa1b, h, N_NODESC, 256, 1);

  // layer 2
  mfma_gemm_lds<256><<<dim3(gm, 1), 256, 0, stream>>>(h, l2w, lin2b, linx, N_NODESC, 128, 0);
  aggregate_v<<<N_NODESC / 4, 256, 0, stream>>>((const uint2*)linx, rp, elist, (uint2*)h2);
  mfma_gemm_lds<128><<<dim3(gm, 2), 256, 0, stream>>>(h2, qe2, qa2b, h, N_NODESC, 256, 1);

  // pool + heads
  pool2<<<NGC, 256, 0, stream>>>((const uint*)h, batch, gbuf);
  head_kernel<<<dim3(NGC / 8, NPC), 128, 0, stream>>>(gbuf, hw1, hb1, hw2, hb2, out);
}

// Round 9
// 244.370 us; speedup vs baseline: 1.1813x; 1.0906x over previous
//
#include <hip/hip_runtime.h>
#include <hip/hip_bf16.h>

#define N_NODESC 50000
#define N_EDGESC 1600000
#define NGC 1024
#define NPC 8
#define NBIN 196          // dst>>8 buckets (256 nodes each)
#define NBLKE 391         // edge chunks of 4096

typedef __attribute__((ext_vector_type(8))) short bf16x8;
typedef __attribute__((ext_vector_type(4))) float f32x4;

__device__ inline ushort f2bf(float f) {
  union { float f; uint u; } v; v.f = f;
  uint u = v.u;
  u += 0x7FFF + ((u >> 16) & 1);
  return (ushort)(u >> 16);
}
__device__ inline float bflo(uint u) {
  union { uint u; float f; } v; v.u = u << 16; return v.f;
}
__device__ inline float bfhi(uint u) {
  union { uint u; float f; } v; v.u = u & 0xFFFF0000u; return v.f;
}

// ---------------- fused prep: weights + features + edge histogram ----------
__global__ __launch_bounds__(256) void megaprep(
    const float* __restrict__ qa1w, const float* __restrict__ qa2w,
    const float* __restrict__ lin1w, const float* __restrict__ lin2w,
    ushort* __restrict__ qe1, ushort* __restrict__ qe2,
    ushort* __restrict__ l1w, ushort* __restrict__ l2w,
    const int* __restrict__ x, const float* __restrict__ e24,
    const float* __restrict__ e72, ushort* __restrict__ feat,
    const int* __restrict__ dst, int* __restrict__ bh) {
  int bid = blockIdx.x, t = threadIdx.x;
  if (bid < 256) {
    const float* qw = (bid < 128) ? qa1w : qa2w;
    ushort* eff = (bid < 128) ? qe1 : qe2;
    int k = (bid & 127) * 2 + (t >> 7);
    int j = t & 127;
    const float* r = qw + (size_t)k * 256;
    float v;
    if (j < 64) v = r[j] + r[128 + j] + r[192 + j];
    else { int j2 = j - 64; v = r[64 + j2] + r[128 + j2] + 2.0f * r[192 + j2]; }
    eff[(size_t)k * 128 + j] = f2bf(v);
  } else if (bid < 304) {
    int i = (bid - 256) * 256 + t;  // < 12288 = 128*96
    int r = i / 96, c = i - r * 96;
    l1w[i] = (c < 68) ? f2bf(lin1w[(size_t)r * 68 + c]) : (ushort)0;
  } else if (bid < 432) {
    int r = bid - 304;
    l2w[(size_t)r * 256 + t] = f2bf(lin2w[(size_t)r * 256 + t]);
  } else if (bid < 1456) {
    const int stride = 1024 * 256;
    for (int i = (bid - 432) * 256 + t; i < N_NODESC * 96; i += stride) {
      int n = i / 96, tt = i - n * 96;
      float v = 0.f;
      if (tt < 4) v = (float)x[n * 4 + tt];
      else if (tt < 36) { int kk = tt - 4;  int f = kk >> 3, c = kk & 7; v = e24[(x[n * 4 + f] % 24) * 8 + c]; }
      else if (tt < 68) { int kk = tt - 36; int f = kk >> 3, c = kk & 7; v = e72[(x[n * 4 + f] % 72) * 8 + c]; }
      feat[i] = f2bf(v);
    }
  } else {
    __shared__ int hist[NBIN];
    int blk = bid - 1456;
    if (t < NBIN) hist[t] = 0;
    __syncthreads();
    int base = blk * 4096;
#pragma unroll
    for (int i = 0; i < 16; ++i) {
      int idx = base + i * 256 + t;
      if (idx < N_EDGESC) atomicAdd(&hist[dst[idx] >> 8], 1);
    }
    __syncthreads();
    if (t < NBIN) bh[(size_t)t * NBLKE + blk] = hist[t];
  }
}

// ---------------- CSR: per-bin scan ----------------
__global__ __launch_bounds__(64) void csr_scan_bins(int* __restrict__ bh, int* __restrict__ bt) {
  int bin = blockIdx.x;
  int lane = threadIdx.x;
  int carry = 0;
  int* row = bh + (size_t)bin * NBLKE;
  for (int c = 0; c < NBLKE; c += 64) {
    int j = c + lane;
    int v = (j < NBLKE) ? row[j] : 0;
    int incl = v;
#pragma unroll
    for (int off = 1; off < 64; off <<= 1) {
      int u = __shfl_up(incl, off, 64);
      if (lane >= off) incl += u;
    }
    if (j < NBLKE) row[j] = carry + incl - v;
    carry += __shfl(incl, 63, 64);
  }
  if (lane == 0) bt[bin] = carry;
}

// ---------------- shared GEMM body (W staged in swizzled LDS) ---------------
template <int K>
__device__ __forceinline__ void gemm_body(ushort* ws, int bx, int by,
    const ushort* __restrict__ A, const ushort* __restrict__ W,
    const float* __restrict__ bias, ushort* __restrict__ C,
    int M, int NC, int relu) {
  int tid = threadIdx.x;
  int lane = tid & 63;
  int wv = tid >> 6;
  int rbase = bx * 128 + wv * 32;
  int colt = by * 128;
  int r16 = lane & 15;
  int kg = (lane >> 4) * 8;

  const char* wt = (const char*)(W + (size_t)colt * K);
#pragma unroll
  for (int i = 0; i < K / 16; ++i) {
    int o = (i * 256 + tid) * 16;
    int col = o / (2 * K);
    int sw = o ^ ((col & 7) << 4);
    *(bf16x8*)((char*)ws + sw) = *(const bf16x8*)(wt + o);
  }
  __syncthreads();

  f32x4 acc[2][8];
#pragma unroll
  for (int m = 0; m < 2; ++m)
#pragma unroll
    for (int n = 0; n < 8; ++n) acc[m][n] = (f32x4){0.f, 0.f, 0.f, 0.f};

  for (int k0 = 0; k0 < K; k0 += 32) {
    int ks = k0 + kg;
    bf16x8 a[2], b[8];
#pragma unroll
    for (int m = 0; m < 2; ++m) {
      int rr = rbase + m * 16 + r16;
      if (rr >= M) rr = M - 1;
      a[m] = *(const bf16x8*)(A + (size_t)rr * K + ks);
    }
#pragma unroll
    for (int n = 0; n < 8; ++n) {
      int cl = n * 16 + r16;
      int byte = (cl * 2 * K + ks * 2) ^ ((cl & 7) << 4);
      b[n] = *(const bf16x8*)((const char*)ws + byte);
    }
#pragma unroll
    for (int m = 0; m < 2; ++m)
#pragma unroll
      for (int n = 0; n < 8; ++n)
        acc[m][n] = __builtin_amdgcn_mfma_f32_16x16x32_bf16(a[m], b[n], acc[m][n], 0, 0, 0);
  }

  int rowoff = (lane >> 4) * 4;
#pragma unroll
  for (int m = 0; m < 2; ++m) {
#pragma unroll
    for (int j = 0; j < 4; ++j) {
      int row = rbase + m * 16 + rowoff + j;
      if (row >= M) continue;
#pragma unroll
      for (int n = 0; n < 8; ++n) {
        int col = colt + n * 16 + r16;
        float v = acc[m][n][j] + bias[col];
        if (relu) v = fmaxf(v, 0.f);
        C[(size_t)row * NC + col] = f2bf(v);
      }
    }
  }
}

template <int K>
__global__ __launch_bounds__(256, 2) void mfma_gemm_lds(
    const ushort* __restrict__ A, const ushort* __restrict__ W,
    const float* __restrict__ bias, ushort* __restrict__ C,
    int M, int NC, int relu) {
  __shared__ ushort ws[128 * K];
  gemm_body<K>(ws, blockIdx.x, blockIdx.y, A, W, bias, C, M, NC, relu);
}

// ---------------- fused: csr_scatter (blocks < NBLKE) ∥ lin1 GEMM ----------
__global__ __launch_bounds__(256, 2) void scatter_lin1(
    const int* __restrict__ src, const int* __restrict__ dst,
    const int* __restrict__ bh, const int* __restrict__ bt, uint* __restrict__ tmp,
    const ushort* __restrict__ feat, const ushort* __restrict__ l1w,
    const float* __restrict__ lin1b, ushort* __restrict__ linx) {
  __shared__ ushort ws[128 * 96];
  int bid = blockIdx.x, t = threadIdx.x;
  if (bid < NBLKE) {
    int* sc = (int*)ws;
    int* cur = sc + 256;
    int v = (t < NBIN) ? bt[t] : 0;
    sc[t] = v;
    __syncthreads();
    for (int off = 1; off < 256; off <<= 1) {
      int u = (t >= off) ? sc[t - off] : 0;
      __syncthreads();
      sc[t] += u;
      __syncthreads();
    }
    if (t < NBIN) cur[t] = (sc[t] - v) + bh[(size_t)t * NBLKE + bid];
    __syncthreads();
    int base = bid * 4096;
#pragma unroll
    for (int i = 0; i < 16; ++i) {
      int idx = base + i * 256 + t;
      if (idx < N_EDGESC) {
        int d = dst[idx];
        uint p = ((uint)d << 16) | (uint)src[idx];
        int pos = atomicAdd(&cur[d >> 8], 1);
        tmp[pos] = p;
      }
    }
  } else {
    gemm_body<96>(ws, bid - NBLKE, 0, feat, l1w, lin1b, linx, N_NODESC, 128, 0);
  }
}

// ---------------- per-bucket counting sort -> elist (ushort) + rp -----------
__global__ __launch_bounds__(256) void csr_bucket_sort(const uint* __restrict__ tmp,
                                                       const int* __restrict__ bt,
                                                       ushort* __restrict__ elist,
                                                       int* __restrict__ rp) {
  __shared__ int sc[256];
  __shared__ int cnt[256];
  int b = blockIdx.x, t = threadIdx.x;
  int v = (t < NBIN) ? bt[t] : 0;
  sc[t] = v;
  __syncthreads();
  for (int off = 1; off < 256; off <<= 1) {
    int u = (t >= off) ? sc[t - off] : 0;
    __syncthreads();
    sc[t] += u;
    __syncthreads();
  }
  int base = (b == 0) ? 0 : sc[b - 1];
  int end = sc[b];
  int total = sc[NBIN - 1];
  __syncthreads();
  cnt[t] = 0;
  __syncthreads();
  for (int i = base + t; i < end; i += 256)
    atomicAdd(&cnt[(tmp[i] >> 16) & 255], 1);
  __syncthreads();
  int cv = cnt[t];
  sc[t] = cv;
  __syncthreads();
  for (int off = 1; off < 256; off <<= 1) {
    int u = (t >= off) ? sc[t - off] : 0;
    __syncthreads();
    sc[t] += u;
    __syncthreads();
  }
  int excl = sc[t] - cv;
  int node = (b << 8) + t;
  if (node < N_NODESC) rp[node] = base + excl;
  if (b == NBIN - 1 && t == 0) rp[N_NODESC] = total;
  cnt[t] = base + excl;  // global cursor
  __syncthreads();
  for (int i = base + t; i < end; i += 256) {
    uint p = tmp[i];
    int pos = atomicAdd(&cnt[(p >> 16) & 255], 1);
    elist[pos] = (ushort)(p & 0xFFFFu);
  }
}

// ---------------- aggregation: h2[n] = 2*linx[n] + sum_{e->n} linx[src] -----
// Row-major [N][128] bf16; wave per node; lane covers cols {2c,2c+1};
// 16 gathers in flight (statically-indexed batch -> registers).
__global__ __launch_bounds__(256) void aggregate2(const uint* __restrict__ lx,
                                                  const int* __restrict__ rp,
                                                  const ushort* __restrict__ elist,
                                                  uint* __restrict__ h2) {
  int wv = threadIdx.x >> 6, lane = threadIdx.x & 63;
  int n = blockIdx.x * 4 + wv;
  int beg = rp[n], end = rp[n + 1];
  uint su = lx[(size_t)n * 64 + lane];
  float a0 = 2.f * bflo(su), a1 = 2.f * bfhi(su);
  int e = beg;
  for (; e + 16 <= end; e += 16) {
    uint r[16];
#pragma unroll
    for (int i = 0; i < 16; ++i) {
      int s = elist[e + i];
      r[i] = lx[(size_t)s * 64 + lane];
    }
#pragma unroll
    for (int i = 0; i < 16; ++i) { a0 += bflo(r[i]); a1 += bfhi(r[i]); }
  }
  for (; e + 4 <= end; e += 4) {
    uint r0 = lx[(size_t)elist[e] * 64 + lane];
    uint r1 = lx[(size_t)elist[e + 1] * 64 + lane];
    uint r2 = lx[(size_t)elist[e + 2] * 64 + lane];
    uint r3 = lx[(size_t)elist[e + 3] * 64 + lane];
    a0 += bflo(r0) + bflo(r1) + bflo(r2) + bflo(r3);
    a1 += bfhi(r0) + bfhi(r1) + bfhi(r2) + bfhi(r3);
  }
  for (; e < end; ++e) {
    uint r0 = lx[(size_t)elist[e] * 64 + lane];
    a0 += bflo(r0);
    a1 += bfhi(r0);
  }
  h2[(size_t)n * 64 + lane] = (uint)f2bf(a0) | ((uint)f2bf(a1) << 16);
}

// ---------------- global mean pool (batch sorted), bf16 input ---------------
__global__ __launch_bounds__(256) void pool2(const uint* __restrict__ h,
                                             const int* __restrict__ batch,
                                             float* __restrict__ g) {
  int gg = blockIdx.x;
  int t = threadIdx.x;
  int j = t & 127, rg = t >> 7;
  int lo = 0, hi = N_NODESC;
  while (lo < hi) { int mid = (lo + hi) >> 1; if (batch[mid] < gg) lo = mid + 1; else hi = mid; }
  int beg = lo;
  hi = N_NODESC;
  while (lo < hi) { int mid = (lo + hi) >> 1; if (batch[mid] < gg + 1) lo = mid + 1; else hi = mid; }
  int end = lo;
  float a0 = 0.f, a1 = 0.f;
  int n = beg + rg;
  for (; n + 2 < end; n += 4) {
    uint u = h[(size_t)n * 128 + j];
    uint u2 = h[(size_t)(n + 2) * 128 + j];
    a0 += bflo(u) + bflo(u2);
    a1 += bfhi(u) + bfhi(u2);
  }
  if (n < end) {
    uint u = h[(size_t)n * 128 + j];
    a0 += bflo(u);
    a1 += bfhi(u);
  }
  __shared__ float s0[128], s1[128];
  if (rg == 1) { s0[j] = a0; s1[j] = a1; }
  __syncthreads();
  if (rg == 0) {
    a0 += s0[j];
    a1 += s1[j];
    float cfac = fmaxf((float)(end - beg), 1.0f);
    g[(size_t)gg * 256 + 2 * j] = a0 / cfac;
    g[(size_t)gg * 256 + 2 * j + 1] = a1 / cfac;
  }
}

// ---------------- per-property heads (8 graphs per block) -------------------
__global__ __launch_bounds__(128) void head_kernel(const float* __restrict__ g,
    const float* __restrict__ w1, const float* __restrict__ b1,
    const float* __restrict__ w2, const float* __restrict__ b2,
    float* __restrict__ out) {
  int p = blockIdx.y;
  int g0 = blockIdx.x * 8;
  int t = threadIdx.x;
  __shared__ float gs[8][256];
  for (int i = t; i < 8 * 256; i += 128)
    gs[i >> 8][i & 255] = g[(size_t)(g0 + (i >> 8)) * 256 + (i & 255)];
  __syncthreads();
  const float4* w4 = (const float4*)(w1 + ((size_t)p * 128 + t) * 256);
  float bv = b1[p * 128 + t];
  float acc[8];
#pragma unroll
  for (int q = 0; q < 8; ++q) acc[q] = bv;
  for (int d4 = 0; d4 < 64; ++d4) {
    float4 wv = w4[d4];
#pragma unroll
    for (int q = 0; q < 8; ++q) {
      acc[q] += gs[q][d4 * 4 + 0] * wv.x + gs[q][d4 * 4 + 1] * wv.y +
                gs[q][d4 * 4 + 2] * wv.z + gs[q][d4 * 4 + 3] * wv.w;
    }
  }
  float w2v = w2[p * 128 + t];
  __shared__ float red[2][8];
  int wave = t >> 6, lane = t & 63;
#pragma unroll
  for (int q = 0; q < 8; ++q) {
    float v = fmaxf(acc[q], 0.f) * w2v;
    for (int o = 32; o > 0; o >>= 1) v += __shfl_down(v, o, 64);
    if (lane == 0) red[wave][q] = v;
  }
  __syncthreads();
  if (t < 8) out[(size_t)(g0 + t) * 8 + p] = red[0][t] + red[1][t] + b2[p];
}

extern "C" void kernel_launch(void* const* d_in, const int* in_sizes, int n_in,
                              void* d_out, int out_size, void* d_ws, size_t ws_size,
                              hipStream_t stream) {
  const int*   x     = (const int*)d_in[0];
  const int*   ei    = (const int*)d_in[1];
  const int*   batch = (const int*)d_in[2];
  const float* emb24 = (const float*)d_in[3];
  const float* emb72 = (const float*)d_in[4];
  const float* lin1w = (const float*)d_in[5];
  const float* lin1b = (const float*)d_in[6];
  const float* qa1w  = (const float*)d_in[7];
  const float* qa1b  = (const float*)d_in[8];
  const float* lin2w = (const float*)d_in[9];
  const float* lin2b = (const float*)d_in[10];
  const float* qa2w  = (const float*)d_in[11];
  const float* qa2b  = (const float*)d_in[12];
  const float* hw1   = (const float*)d_in[13];
  const float* hb1   = (const float*)d_in[14];
  const float* hw2   = (const float*)d_in[15];
  const float* hb2   = (const float*)d_in[16];
  float* out = (float*)d_out;

  const int* srcv = ei;
  const int* dstv = ei + N_EDGESC;

  char* wsb = (char*)d_ws;
  size_t off = 0;
  auto alloc = [&](size_t b) { char* p = wsb + off; off += (b + 255) & ~(size_t)255; return p; };
  ushort* feat  = (ushort*)alloc((size_t)N_NODESC * 96 * 2);
  ushort* linx  = (ushort*)alloc((size_t)N_NODESC * 128 * 2);   // row-major [N][128]
  ushort* h2    = (ushort*)alloc((size_t)N_NODESC * 128 * 2);   // row-major
  ushort* h     = (ushort*)alloc((size_t)N_NODESC * 256 * 2);   // row-major
  float*  gbuf  = (float*)alloc((size_t)NGC * 256 * 4);
  ushort* qe1   = (ushort*)alloc(256 * 128 * 2);
  ushort* qe2   = (ushort*)alloc(256 * 128 * 2);
  ushort* l1w   = (ushort*)alloc(128 * 96 * 2);
  ushort* l2w   = (ushort*)alloc(128 * 256 * 2);
  int*    rp    = (int*)alloc((size_t)(N_NODESC + 1) * 4);
  ushort* elist = (ushort*)alloc((size_t)N_EDGESC * 2);
  int*    bh    = (int*)alloc((size_t)NBIN * NBLKE * 4);
  int*    bt    = (int*)alloc((size_t)NBIN * 4);
  uint*   tmp   = (uint*)h;  // alias: h not written until qa1 (after CSR done)

  // fused prep: weights + features + histogram
  megaprep<<<1847, 256, 0, stream>>>(qa1w, qa2w, lin1w, lin2w, qe1, qe2, l1w, l2w,
                                     x, emb24, emb72, feat, dstv, bh);
  csr_scan_bins<<<NBIN, 64, 0, stream>>>(bh, bt);

  int gm = (N_NODESC + 127) / 128;  // 391

  // scatter ∥ lin1 GEMM (independent)
  scatter_lin1<<<NBLKE + gm, 256, 0, stream>>>(srcv, dstv, bh, bt, tmp,
                                               feat, l1w, lin1b, linx);
  csr_bucket_sort<<<NBIN, 256, 0, stream>>>(tmp, bt, elist, rp);

  // layer 1
  aggregate2<<<N_NODESC / 4, 256, 0, stream>>>((const uint*)linx, rp, elist, (uint*)h2);
  mfma_gemm_lds<128><<<dim3(gm, 2), 256, 0, stream>>>(h2, qe1, qa1b, h, N_NODESC, 256, 1);

  // layer 2
  mfma_gemm_lds<256><<<dim3(gm, 1), 256, 0, stream>>>(h, l2w, lin2b, linx, N_NODESC, 128, 0);
  aggregate2<<<N_NODESC / 4, 256, 0, stream>>>((const uint*)linx, rp, elist, (uint*)h2);
  mfma_gemm_lds<128><<<dim3(gm, 2), 256, 0, stream>>>(h2, qe2, qa2b, h, N_NODESC, 256, 1);

  // pool + heads
  pool2<<<NGC, 256, 0, stream>>>((const uint*)h, batch, gbuf);
  head_kernel<<<dim3(NGC / 8, NPC), 128, 0, stream>>>(gbuf, hw1, hb1, hw2, hb2, out);
}